// Round 1
// baseline (251.974 us; speedup 1.0000x reference)
//
#include <hip/hip_runtime.h>

// Problem constants (from reference): U=4 users, NT=8 antennas,
// BATCH=128, CWH=49152 -> per-user plane = 6,291,456 fp32 elements.
#define UU 4
#define NTT 8
#define BC 6291456      // BATCH * CWH
#define BC4 1572864     // BC / 4 (float4 groups per user plane)

__global__ __launch_bounds__(256) void chn_mu_miso_kernel(
    const float* __restrict__ x,      // [U, B*C]
    const float* __restrict__ W,      // [NT, U]
    const float* __restrict__ H,      // [NT, U]
    const float* __restrict__ P,      // [U]
    const float* __restrict__ stddev, // [U]
    const float* __restrict__ noise,  // [U, B*C]
    float* __restrict__ out)          // [U, B*C]
{
    // ---- Precompute the 4x4 mixing matrix + noise coefs (wave-uniform) ----
    // coef[u][v] = sqrtP[v] * (sum_n H[n,u] * W[n,v]) / amp[u]
    // nco[u]     = stddev[u] / amp[u],  amp[u] = sqrtP[u] * sum_n H[n,u]*W[n,u]
    float sqrtP[UU];
#pragma unroll
    for (int v = 0; v < UU; ++v) sqrtP[v] = sqrtf(P[v]);

    float coef[UU][UU];
    float nco[UU];
#pragma unroll
    for (int u = 0; u < UU; ++u) {
        float hw = 0.0f;
#pragma unroll
        for (int n = 0; n < NTT; ++n) hw += H[n * UU + u] * W[n * UU + u];
        const float inv_amp = 1.0f / (sqrtP[u] * hw);
#pragma unroll
        for (int v = 0; v < UU; ++v) {
            float m = 0.0f;
#pragma unroll
            for (int n = 0; n < NTT; ++n) m += H[n * UU + u] * W[n * UU + v];
            coef[u][v] = m * sqrtP[v] * inv_amp;
        }
        nco[u] = stddev[u] * inv_amp;
    }

    // ---- Memory-bound mixing loop: one float4 per thread per user ----
    const int i4 = blockIdx.x * blockDim.x + threadIdx.x;
    if (i4 >= BC4) return;

    const float4* __restrict__ x4 = (const float4*)x;
    const float4* __restrict__ n4 = (const float4*)noise;
    float4* __restrict__ o4 = (float4*)out;

    float4 xv[UU];
    float4 nv[UU];
#pragma unroll
    for (int v = 0; v < UU; ++v) xv[v] = x4[v * BC4 + i4];
#pragma unroll
    for (int u = 0; u < UU; ++u) nv[u] = n4[u * BC4 + i4];

#pragma unroll
    for (int u = 0; u < UU; ++u) {
        float4 acc;
        acc.x = nco[u] * nv[u].x;
        acc.y = nco[u] * nv[u].y;
        acc.z = nco[u] * nv[u].z;
        acc.w = nco[u] * nv[u].w;
#pragma unroll
        for (int v = 0; v < UU; ++v) {
            acc.x += coef[u][v] * xv[v].x;
            acc.y += coef[u][v] * xv[v].y;
            acc.z += coef[u][v] * xv[v].z;
            acc.w += coef[u][v] * xv[v].w;
        }
        o4[u * BC4 + i4] = acc;
    }
}

extern "C" void kernel_launch(void* const* d_in, const int* in_sizes, int n_in,
                              void* d_out, int out_size, void* d_ws, size_t ws_size,
                              hipStream_t stream) {
    const float* x      = (const float*)d_in[0];
    const float* W      = (const float*)d_in[1];
    const float* H      = (const float*)d_in[2];
    const float* P      = (const float*)d_in[3];
    const float* stddev = (const float*)d_in[4];
    const float* noise  = (const float*)d_in[5];
    float* out = (float*)d_out;

    const int threads = 256;
    const int blocks = (BC4 + threads - 1) / threads;  // 6144
    chn_mu_miso_kernel<<<blocks, threads, 0, stream>>>(x, W, H, P, stddev, noise, out);
}

// Round 3
// 237.220 us; speedup vs baseline: 1.0622x; 1.0622x over previous
//
#include <hip/hip_runtime.h>

// Problem constants: U=4 users, NT=8 antennas, BATCH*CWH = 6,291,456 fp32/plane.
#define UU 4
#define NTT 8
#define BC4 1572864            // (BATCH*CWH)/4 float4 groups per plane
#define THREADS 256
#define TILE 4                 // float4 positions per thread
#define NBLOCKS (BC4 / (THREADS * TILE))   // 1536, exact

typedef float f32x4 __attribute__((ext_vector_type(4)));  // native vector: OK for nontemporal builtins

// ---- 1-wave setup: compute the 4x4 mixing matrix + 4 noise coefs into ws ----
// cf[u*4+v] = sqrtP[v] * (sum_n H[n,u]*W[n,v]) / amp[u]
// cf[16+u]  = stddev[u] / amp[u],   amp[u] = sqrtP[u] * sum_n H[n,u]*W[n,u]
__global__ __launch_bounds__(64) void coef_setup(
    const float* __restrict__ W, const float* __restrict__ H,
    const float* __restrict__ P, const float* __restrict__ stddev,
    float* __restrict__ cf)
{
    if (threadIdx.x != 0) return;
    float sqrtP[UU];
#pragma unroll
    for (int v = 0; v < UU; ++v) sqrtP[v] = sqrtf(P[v]);
#pragma unroll
    for (int u = 0; u < UU; ++u) {
        float hw = 0.0f;
#pragma unroll
        for (int n = 0; n < NTT; ++n) hw += H[n * UU + u] * W[n * UU + u];
        const float inv_amp = 1.0f / (sqrtP[u] * hw);
#pragma unroll
        for (int v = 0; v < UU; ++v) {
            float m = 0.0f;
#pragma unroll
            for (int n = 0; n < NTT; ++n) m += H[n * UU + u] * W[n * UU + v];
            cf[u * UU + v] = m * sqrtP[v] * inv_amp;
        }
        cf[16 + u] = stddev[u] * inv_amp;
    }
}

// ---- Memory-bound mixing: 16 KB contiguous per plane per block ----
__global__ __launch_bounds__(THREADS) void mix_kernel(
    const f32x4* __restrict__ x4,   // [U][BC4]
    const f32x4* __restrict__ n4,   // [U][BC4]
    const float* __restrict__ cf,   // [20] coefs in ws (uniform address)
    f32x4* __restrict__ o4)         // [U][BC4]
{
    // Uniform loads -> compiler scalarizes into SGPRs.
    float c[UU][UU], nc[UU];
#pragma unroll
    for (int u = 0; u < UU; ++u) {
#pragma unroll
        for (int v = 0; v < UU; ++v) c[u][v] = cf[u * UU + v];
        nc[u] = cf[16 + u];
    }

    const int base = blockIdx.x * (THREADS * TILE) + threadIdx.x;
#pragma unroll
    for (int j = 0; j < TILE; ++j) {
        const int i4 = base + j * THREADS;

        // x and noise are each read exactly once -> stream (nontemporal) loads.
        f32x4 xv[UU];
#pragma unroll
        for (int v = 0; v < UU; ++v)
            xv[v] = __builtin_nontemporal_load(&x4[v * BC4 + i4]);

#pragma unroll
        for (int u = 0; u < UU; ++u) {
            const f32x4 nv = __builtin_nontemporal_load(&n4[u * BC4 + i4]);
            f32x4 acc = nc[u] * nv;
#pragma unroll
            for (int v = 0; v < UU; ++v)
                acc += c[u][v] * xv[v];
            // out has zero reuse: stream past L2/L3.
            __builtin_nontemporal_store(acc, &o4[u * BC4 + i4]);
        }
    }
}

extern "C" void kernel_launch(void* const* d_in, const int* in_sizes, int n_in,
                              void* d_out, int out_size, void* d_ws, size_t ws_size,
                              hipStream_t stream) {
    const float* x      = (const float*)d_in[0];
    const float* W      = (const float*)d_in[1];
    const float* H      = (const float*)d_in[2];
    const float* P      = (const float*)d_in[3];
    const float* stddev = (const float*)d_in[4];
    const float* noise  = (const float*)d_in[5];
    float* out = (float*)d_out;
    float* cf  = (float*)d_ws;   // 20 floats of scratch

    coef_setup<<<1, 64, 0, stream>>>(W, H, P, stddev, cf);
    mix_kernel<<<NBLOCKS, THREADS, 0, stream>>>(
        (const f32x4*)x, (const f32x4*)noise, cf, (f32x4*)out);
}